// Round 9
// baseline (136.945 us; speedup 1.0000x reference)
//
#include <hip/hip_runtime.h>
#include <hip/hip_bf16.h>
#include <cstddef>

typedef __attribute__((ext_vector_type(8))) short short8;
typedef __attribute__((ext_vector_type(4))) float floatx4;
typedef __hip_bfloat16 bf16;

#define NB 8
#define NC 256
#define ND 128
#define NN 3072
#define NBLK 48           /* proj blocks per batch = NN/64 */
#define BN_EPS 1e-5f

static __device__ __forceinline__ short f2s(float v) {
    bf16 h = __float2bfloat16(v);
    return *reinterpret_cast<short*>(&h);
}
static __device__ __forceinline__ float s2f(short v) {
    bf16 h = *reinterpret_cast<bf16*>(&v);
    return __bfloat162float(h);
}

// setup: Wall[r][c] bf16 = [phi_w; g_w; theta_w]  (384 x 256, 192 KB, L2-hot)
__global__ __launch_bounds__(256) void setup_kernel(
    const float* __restrict__ phi_w, const float* __restrict__ g_w,
    const float* __restrict__ theta_w, short* __restrict__ Wall)
{
    int t = threadIdx.x;
    int r = blockIdx.x;
    const float* src = (r < 128) ? (phi_w + (size_t)r * NC)
                     : (r < 256) ? (g_w + (size_t)(r - 128) * NC)
                                 : (theta_w + (size_t)(r - 256) * NC);
    Wall[(size_t)r * NC + t] = f2s(src[t]);
}

// ---------------------------------------------------------------------------
// proj: grid (48, 8), 384 threads = 6 waves; wave w owns rows w*64..w*64+63
// of [phi(0-127); g(128-255); theta(256-383)], n-tile 64.
// - x fp32 -> bf16 LDS-transposed; SOFTWARE-PIPELINED: chunk k+1 prefetched
//   into registers while chunk k's MFMA runs (hides ~900cyc HBM latency).
// - A-frags hoisted from Wall (L2) ahead of the LDS B-reads each chunk.
// - M-stage partials stored bf16, LANE-MAJOR (wave-contiguous 128B stores):
//   idx = wave*4096 + ((i*4+j)*4+r)*64 + lane  <->  (e,d) bijective.
// ---------------------------------------------------------------------------
__global__ __launch_bounds__(384)
void proj_kernel(const float* __restrict__ x, const short* __restrict__ Wall,
                 const float* __restrict__ phi_b, const float* __restrict__ g_b,
                 const float* __restrict__ theta_b,
                 short* __restrict__ thDN, short* __restrict__ Mpart)
{
    __shared__ short PGs[256][72];  // phi/g projections [row][n]
    __shared__ short Xs[64][72];    // x chunk [n][c]
    int b = blockIdx.y;
    int n0 = blockIdx.x * 64;
    int t = threadIdx.x;
    int lane = t & 63;
    int wave = t >> 6;              // 0..5
    int lm = lane & 15;
    int lk = (lane >> 4) * 8;
    int sn = t & 63;                // staging n index
    int cg = t >> 6;                // staging c-group

    const float* xb = x + (size_t)b * NC * NN;

    floatx4 zero = {0.f, 0.f, 0.f, 0.f};
    floatx4 acc[4][4];
#pragma unroll
    for (int i = 0; i < 4; ++i)
#pragma unroll
        for (int j = 0; j < 4; ++j) acc[i][j] = zero;

    // prefetch x chunk 0 into registers
    float v[16];
    if (t < 256) {
        const float* src = xb + (size_t)(cg * 16) * NN + n0 + sn;
#pragma unroll
        for (int j = 0; j < 16; ++j) v[j] = src[(size_t)j * NN];
    }

#pragma unroll
    for (int kt = 0; kt < NC; kt += 64) {
        __syncthreads();
        if (t < 256) {      // convert prefetched chunk into Xs (transposed)
            short8 s0, s1;
#pragma unroll
            for (int j = 0; j < 8; ++j) { s0[j] = f2s(v[j]); s1[j] = f2s(v[8 + j]); }
            *(short8*)&Xs[sn][cg * 16]     = s0;
            *(short8*)&Xs[sn][cg * 16 + 8] = s1;
        }
        __syncthreads();
        if (t < 256 && kt + 64 < NC) {   // prefetch next chunk during MFMA
            const float* src = xb + (size_t)(kt + 64 + cg * 16) * NN + n0 + sn;
#pragma unroll
            for (int j = 0; j < 16; ++j) v[j] = src[(size_t)j * NN];
        }
        // hoist A-frags for both kk halves (global/L2, barrier-independent)
        short8 a0[4], a1[4];
#pragma unroll
        for (int i = 0; i < 4; ++i) {
            const short* wp = Wall + (size_t)(wave * 64 + i * 16 + lm) * NC + kt + lk;
            a0[i] = *(const short8*)(wp);
            a1[i] = *(const short8*)(wp + 32);
        }
        short8 bfr[4];
#pragma unroll
        for (int j = 0; j < 4; ++j)
            bfr[j] = *(const short8*)&Xs[j * 16 + lm][lk];
#pragma unroll
        for (int i = 0; i < 4; ++i)
#pragma unroll
            for (int j = 0; j < 4; ++j)
                acc[i][j] = __builtin_amdgcn_mfma_f32_16x16x32_bf16(
                    a0[i], bfr[j], acc[i][j], 0, 0, 0);
#pragma unroll
        for (int j = 0; j < 4; ++j)
            bfr[j] = *(const short8*)&Xs[j * 16 + lm][32 + lk];
#pragma unroll
        for (int i = 0; i < 4; ++i)
#pragma unroll
            for (int j = 0; j < 4; ++j)
                acc[i][j] = __builtin_amdgcn_mfma_f32_16x16x32_bf16(
                    a1[i], bfr[j], acc[i][j], 0, 0, 0);
    }

    // C/D layout: col = lane&15, row = (lane>>4)*4 + reg
    int row0 = wave * 64 + (lane >> 4) * 4;

    if (wave < 4) {    // phi/g: +bias -> PGs[row][n]
#pragma unroll
        for (int i = 0; i < 4; ++i) {
#pragma unroll
            for (int r = 0; r < 4; ++r) {
                int row = row0 + i * 16 + r;
                float bv = (row < 128) ? phi_b[row] : g_b[row - 128];
#pragma unroll
                for (int j = 0; j < 4; ++j)
                    PGs[row][lm + j * 16] = f2s(acc[i][j][r] + bv);
            }
        }
    } else {           // theta: +bias -> thDN[b][d][n]
        short* Tb = thDN + (size_t)b * ND * NN;
#pragma unroll
        for (int i = 0; i < 4; ++i) {
#pragma unroll
            for (int r = 0; r < 4; ++r) {
                int d = row0 - 256 + i * 16 + r;
                float bv = theta_b[d];
#pragma unroll
                for (int j = 0; j < 4; ++j)
                    Tb[(size_t)d * NN + n0 + lm + j * 16] =
                        f2s(acc[i][j][r] + bv);
            }
        }
    }
    __syncthreads();

    // M partial: waves 0-3, 64x64 tiles of phi . g^T over K=n=64.
    // bf16, lane-major layout -> every store is a 128B wave-contiguous run.
    if (wave < 4) {
        floatx4 macc[4][4];
#pragma unroll
        for (int i = 0; i < 4; ++i)
#pragma unroll
            for (int j = 0; j < 4; ++j) macc[i][j] = zero;
        int wr = wave >> 1, wc = wave & 1;
#pragma unroll
        for (int kk = 0; kk < 64; kk += 32) {
            short8 af[4], bg[4];
#pragma unroll
            for (int i = 0; i < 4; ++i)
                af[i] = *(const short8*)&PGs[wr * 64 + i * 16 + lm][kk + lk];
#pragma unroll
            for (int j = 0; j < 4; ++j)
                bg[j] = *(const short8*)&PGs[128 + wc * 64 + j * 16 + lm][kk + lk];
#pragma unroll
            for (int i = 0; i < 4; ++i)
#pragma unroll
                for (int j = 0; j < 4; ++j)
                    macc[i][j] = __builtin_amdgcn_mfma_f32_16x16x32_bf16(
                        af[i], bg[j], macc[i][j], 0, 0, 0);
        }
        short* Mf = Mpart + ((size_t)b * NBLK + blockIdx.x) * 16384
                  + (size_t)wave * 4096 + lane;
        const float sc = 1.f / (float)NN;
#pragma unroll
        for (int i = 0; i < 4; ++i)
#pragma unroll
            for (int j = 0; j < 4; ++j)
#pragma unroll
                for (int r = 0; r < 4; ++r)
                    Mf[(((i * 4 + j) * 4) + r) * 64] = f2s(macc[i][j][r] * sc);
    }
}

// reduce: sum 48 bf16 partials (fp32 accum) -> Mb16[b][e][d] bf16.
// Lane-major input index -> (e,d) decoded here; short8 per thread, all
// loads/stores coalesced. grid 64 x 256 (16384 threads, 8 elems each).
__global__ __launch_bounds__(256)
void reduce_kernel(const short* __restrict__ Mpart, short* __restrict__ Mb16)
{
    int tid = blockIdx.x * 256 + threadIdx.x;   // 0..16383
    int b = tid >> 11;                           // 2048 threads per batch
    int idx = (tid & 2047) * 8;                  // element index 0..16383
    int wave2 = idx >> 12;
    int rem = idx & 4095;
    int ijr = rem >> 6;                          // (i*4+j)*4 + r
    int lane0 = rem & 63;                        // multiple of 8
    int i = ijr >> 4, j = (ijr >> 2) & 3, r = ijr & 3;
    int wr = wave2 >> 1, wc = wave2 & 1;
    int e = wr * 64 + (lane0 >> 4) * 4 + i * 16 + r;
    int d0 = wc * 64 + (lane0 & 15) + j * 16;

    const short* src = Mpart + (size_t)b * NBLK * 16384 + idx;
    float s[8] = {0.f, 0.f, 0.f, 0.f, 0.f, 0.f, 0.f, 0.f};
#pragma unroll 6
    for (int p = 0; p < NBLK; ++p) {
        short8 vv = *(const short8*)(src + (size_t)p * 16384);
#pragma unroll
        for (int k = 0; k < 8; ++k) s[k] += s2f(vv[k]);
    }
    short8 o;
#pragma unroll
    for (int k = 0; k < 8; ++k) o[k] = f2s(s[k]);
    *(short8*)(Mb16 + (size_t)b * 16384 + (size_t)e * ND + d0) = o;
}

// ---------------------------------------------------------------------------
// final: grid (24, 2, 8), 256 threads.
// Stage 1: P2tile[c][e] = inv[c] * sum_d w_w[c][d]*M[e][d]; M from Mb16
//          (bf16 (e,d) row-major = B layout). -> P2s LDS (A-layout).
// Stage 2: out[c][n] = sum_e P2[c][e]*theta[n][e] + bias2[c] + x[c][n].
// ---------------------------------------------------------------------------
__global__ __launch_bounds__(256)
void final_kernel(const short* __restrict__ Mb16, const short* __restrict__ thDN,
                  const float* __restrict__ w_w, const float* __restrict__ w_b,
                  const float* __restrict__ gamma, const float* __restrict__ beta,
                  const float* __restrict__ mean, const float* __restrict__ var,
                  const float* __restrict__ x, float* __restrict__ out)
{
    __shared__ short As[128][72];
    __shared__ short Bs[128][72];
    __shared__ short P2s[128][136];
    int b = blockIdx.z;
    int tile_m = blockIdx.y * 128;   // c tile
    int tile_n = blockIdx.x * 128;   // n tile
    int t = threadIdx.x;
    int lane = t & 63;
    int wave = t >> 6;
    int wr = wave >> 1, wc = wave & 1;
    int lm = lane & 15;
    int lk = (lane >> 4) * 8;
    int ch = (t & 7) * 8;
    int r0 = t >> 3;

    const short* Mb = Mb16 + (size_t)b * ND * ND;

    floatx4 zero = {0.f, 0.f, 0.f, 0.f};
    floatx4 acc[4][4];
#pragma unroll
    for (int i = 0; i < 4; ++i)
#pragma unroll
        for (int j = 0; j < 4; ++j) acc[i][j] = zero;

    // ---- stage 1: P2tile = w_w(c,d) . M(e,d)^T, K = d = 128
#pragma unroll
    for (int kt = 0; kt < ND; kt += 64) {
        __syncthreads();
#pragma unroll
        for (int p = 0; p < 4; ++p) {
            int r = r0 + p * 32;
            const float* ap = w_w + (size_t)(tile_m + r) * ND + kt + ch;
            floatx4 a0 = *(const floatx4*)ap, a1 = *(const floatx4*)(ap + 4);
            short8 sa;
#pragma unroll
            for (int j = 0; j < 4; ++j) { sa[j] = f2s(a0[j]); sa[4 + j] = f2s(a1[j]); }
            *(short8*)&As[r][ch] = sa;
            *(short8*)&Bs[r][ch] = *(const short8*)(Mb + (size_t)r * ND + kt + ch);
        }
        __syncthreads();
#pragma unroll
        for (int kk = 0; kk < 64; kk += 32) {
            short8 af[4], bfr[4];
#pragma unroll
            for (int i = 0; i < 4; ++i)
                af[i] = *(const short8*)&As[wr * 64 + i * 16 + lm][kk + lk];
#pragma unroll
            for (int j = 0; j < 4; ++j)
                bfr[j] = *(const short8*)&Bs[wc * 64 + j * 16 + lm][kk + lk];
#pragma unroll
            for (int i = 0; i < 4; ++i)
#pragma unroll
                for (int j = 0; j < 4; ++j)
                    acc[i][j] = __builtin_amdgcn_mfma_f32_16x16x32_bf16(
                        af[i], bfr[j], acc[i][j], 0, 0, 0);
        }
    }

    // scale by inv[c], deposit P2s[c_local][e] (A-operand layout for stage 2)
    {
        int row0 = wr * 64 + (lane >> 4) * 4;
        int col0 = wc * 64 + lm;
#pragma unroll
        for (int i = 0; i < 4; ++i) {
#pragma unroll
            for (int r = 0; r < 4; ++r) {
                int cl = row0 + i * 16 + r;
                int c = tile_m + cl;
                float iv = gamma[c] * rsqrtf(var[c] + BN_EPS);
#pragma unroll
                for (int j = 0; j < 4; ++j)
                    P2s[cl][col0 + j * 16] = f2s(acc[i][j][r] * iv);
            }
        }
    }

    // ---- stage 2: out = P2 . theta^T, K = e = 128; theta from thDN[d][n]
    floatx4 acc2[4][4];
#pragma unroll
    for (int i = 0; i < 4; ++i)
#pragma unroll
        for (int j = 0; j < 4; ++j) acc2[i][j] = zero;

    const short* Tb = thDN + (size_t)b * ND * NN;
#pragma unroll
    for (int kt = 0; kt < ND; kt += 64) {
        __syncthreads();
        {   // stage Bs[n(128)][d(64)] from thDN rows (transpose)
            int dl = t & 63;
            int ng = t >> 6;
            const short* src = Tb + (size_t)(kt + dl) * NN + tile_n + ng * 32;
#pragma unroll
            for (int q = 0; q < 4; ++q) {
                short8 vv = *(const short8*)(src + q * 8);
#pragma unroll
                for (int jj = 0; jj < 8; ++jj)
                    Bs[ng * 32 + q * 8 + jj][dl] = vv[jj];
            }
        }
        __syncthreads();
#pragma unroll
        for (int kk = 0; kk < 64; kk += 32) {
            short8 af[4], bfr[4];
#pragma unroll
            for (int i = 0; i < 4; ++i)
                af[i] = *(const short8*)&P2s[wr * 64 + i * 16 + lm][kt + kk + lk];
#pragma unroll
            for (int j = 0; j < 4; ++j)
                bfr[j] = *(const short8*)&Bs[wc * 64 + j * 16 + lm][kk + lk];
#pragma unroll
            for (int i = 0; i < 4; ++i)
#pragma unroll
                for (int j = 0; j < 4; ++j)
                    acc2[i][j] = __builtin_amdgcn_mfma_f32_16x16x32_bf16(
                        af[i], bfr[j], acc2[i][j], 0, 0, 0);
        }
    }

    // epilogue: + bias2[c] + x residual -> fp32 out
    int crow0 = tile_m + wr * 64 + (lane >> 4) * 4;
    int col0 = tile_n + wc * 64 + lm;
    float* Cf = out + (size_t)b * NC * NN;
    const float* Rg = x + (size_t)b * NC * NN;
#pragma unroll
    for (int i = 0; i < 4; ++i) {
#pragma unroll
        for (int r = 0; r < 4; ++r) {
            int c = crow0 + i * 16 + r;
            float iv = gamma[c] * rsqrtf(var[c] + BN_EPS);
            float b2 = iv * (w_b[c] - mean[c]) + beta[c];
#pragma unroll
            for (int j = 0; j < 4; ++j) {
                size_t idx = (size_t)c * NN + col0 + j * 16;
                Cf[idx] = acc2[i][j][r] + b2 + Rg[idx];
            }
        }
    }
}

extern "C" void kernel_launch(void* const* d_in, const int* in_sizes, int n_in,
                              void* d_out, int out_size, void* d_ws, size_t ws_size,
                              hipStream_t stream)
{
    const float* x       = (const float*)d_in[0];
    const float* g_w     = (const float*)d_in[1];
    const float* g_b     = (const float*)d_in[2];
    const float* theta_w = (const float*)d_in[3];
    const float* theta_b = (const float*)d_in[4];
    const float* phi_w   = (const float*)d_in[5];
    const float* phi_b   = (const float*)d_in[6];
    const float* w_w     = (const float*)d_in[7];
    const float* w_b     = (const float*)d_in[8];
    const float* gamma   = (const float*)d_in[9];
    const float* beta    = (const float*)d_in[10];
    const float* mean    = (const float*)d_in[11];
    const float* var     = (const float*)d_in[12];
    (void)in_sizes; (void)n_in; (void)out_size; (void)ws_size;

    char* w = (char*)d_ws;
    short* thDN  = (short*)w; w += (size_t)NB * ND * NN * 2;         // 6.3 MB
    short* Mpart = (short*)w; w += (size_t)NB * NBLK * ND * ND * 2;  // 12.6 MB
    short* Mb16  = (short*)w; w += (size_t)NB * ND * ND * 2;         // 256 KB
    short* Wall  = (short*)w; w += (size_t)384 * NC * 2;             // 192 KB

    setup_kernel<<<dim3(384), dim3(256), 0, stream>>>(
        phi_w, g_w, theta_w, Wall);

    proj_kernel<<<dim3(NN / 64, NB), dim3(384), 0, stream>>>(
        x, Wall, phi_b, g_b, theta_b, thDN, Mpart);

    reduce_kernel<<<dim3(64), dim3(256), 0, stream>>>(Mpart, Mb16);

    final_kernel<<<dim3(NN / 128, NC / 128, NB), 256, 0, stream>>>(
        Mb16, thDN, w_w, w_b, gamma, beta, mean, var, x, (float*)d_out);
}